// Round 1
// baseline (6470.366 us; speedup 1.0000x reference)
//
#include <hip/hip_runtime.h>
#include <cstddef>

#define GAT_EPS 1e-16f

// ---- degree/sum over original edges for self-loop fill_value='mean' ----
__global__ void k_deg(const int* __restrict__ dst, const float* __restrict__ ew,
                      float* __restrict__ sums, float* __restrict__ cnt, int E) {
    int i = blockIdx.x * blockDim.x + threadIdx.x;
    if (i < E) {
        int d = dst[i];
        atomicAdd(&sums[d], ew[i]);
        atomicAdd(&cnt[d], 1.0f);
    }
}

__global__ void k_loopfin(const float* __restrict__ sums, const float* __restrict__ cnt,
                          float* __restrict__ loopat, int N) {
    int i = blockIdx.x * blockDim.x + threadIdx.x;
    if (i < N) loopat[i] = sums[i] / fmaxf(cnt[i], 1.0f);
}

// ---- per-head edge-attr dot constants: wd[h] = sum_c We[h*32+c]*ae[h*32+c] ----
__global__ void k_wedot(const float* __restrict__ we1, const float* __restrict__ ae1,
                        const float* __restrict__ we2, const float* __restrict__ ae2,
                        float* __restrict__ wd) {
    int t = threadIdx.x;  // 128
    float v1 = we1[t] * ae1[t];
    float v2 = we2[t] * ae2[t];
#pragma unroll
    for (int off = 16; off; off >>= 1) {
        v1 += __shfl_xor(v1, off);
        v2 += __shfl_xor(v2, off);
    }
    if ((t & 31) == 0) { wd[t >> 5] = v1; wd[4 + (t >> 5)] = v2; }
}

// ---- layer-1 GEMM: xs = x @ W1^T  (K=64), plus a_src/a_dst head reductions ----
__global__ void k_gemm1(const float* __restrict__ x, const float* __restrict__ W,
                        const float* __restrict__ as_, const float* __restrict__ ad_,
                        float* __restrict__ xs, float* __restrict__ asrc,
                        float* __restrict__ adst, int N) {
    int n = blockIdx.x;
    int t = threadIdx.x;  // 128
    __shared__ float Wsh[8320];   // 128 rows, stride 65 (pad kills bank conflicts)
    __shared__ float xrow[64];
    for (int idx = t; idx < 8192; idx += 128) Wsh[idx + (idx >> 6)] = W[idx];
    if (t < 64) xrow[t] = x[(size_t)n * 64 + t];
    __syncthreads();
    const float* wr = &Wsh[t * 65];
    float a = 0.f;
#pragma unroll
    for (int k = 0; k < 64; k++) a += xrow[k] * wr[k];
    xs[(size_t)n * 128 + t] = a;
    float vs = a * as_[t], vd = a * ad_[t];
#pragma unroll
    for (int off = 16; off; off >>= 1) {
        vs += __shfl_xor(vs, off);
        vd += __shfl_xor(vd, off);
    }
    if ((t & 31) == 0) {
        asrc[(size_t)n * 4 + (t >> 5)] = vs;
        adst[(size_t)n * 4 + (t >> 5)] = vd;
    }
}

// ---- fused edge pass: w=exp(leakyrelu(alpha)); denom[dst]+=w; acc[dst]+=w*xs[src] ----
__global__ void k_edge(const int* __restrict__ src, const int* __restrict__ dst,
                       const float* __restrict__ ew, const float* __restrict__ loopat,
                       const float* __restrict__ xs, const float* __restrict__ asrc,
                       const float* __restrict__ adst, const float* __restrict__ wedot,
                       float* __restrict__ acc, float* __restrict__ denom,
                       int E, int Etot) {
    int g = (blockIdx.x * blockDim.x + threadIdx.x) >> 5;  // one 32-lane group per edge
    if (g >= Etot) return;
    int lane = threadIdx.x & 63;
    int sub = lane & 31;
    int s, d; float ea;
    if (g < E) { s = src[g]; d = dst[g]; ea = ew[g]; }
    else       { s = g - E; d = s;       ea = loopat[s]; }
    float w = 0.f;
    if (sub < 4) {
        float al = asrc[(size_t)s * 4 + sub] + adst[(size_t)d * 4 + sub] + ea * wedot[sub];
        al = al > 0.f ? al : 0.2f * al;
        w = expf(al);
        atomicAdd(&denom[(size_t)d * 4 + sub], w);
    }
    int srcLane = (lane & 32) | (sub >> 3);
    float wb = __shfl(w, srcLane);
    float4 v = reinterpret_cast<const float4*>(xs)[(size_t)s * 32 + sub];
    float* ap = &acc[(size_t)d * 128 + sub * 4];
    atomicAdd(ap + 0, v.x * wb);
    atomicAdd(ap + 1, v.y * wb);
    atomicAdd(ap + 2, v.z * wb);
    atomicAdd(ap + 3, v.w * wb);
}

// ---- layer-1 finalize (mean/bias/relu) fused with layer-2 GEMM (K=32) ----
__global__ void k_node2(const float* __restrict__ acc, const float* __restrict__ denom,
                        const float* __restrict__ b1, const float* __restrict__ W2,
                        const float* __restrict__ as_, const float* __restrict__ ad_,
                        float* __restrict__ xs, float* __restrict__ asrc,
                        float* __restrict__ adst, int N) {
    int n = blockIdx.x, t = threadIdx.x;  // 128
    __shared__ float Wsh[4224];   // 128 rows, stride 33
    __shared__ float h1[32];
    for (int idx = t; idx < 4096; idx += 128) Wsh[idx + (idx >> 5)] = W2[idx];
    if (t < 32) {
        float m = 0.f;
#pragma unroll
        for (int h = 0; h < 4; h++)
            m += acc[(size_t)n * 128 + h * 32 + t] / (denom[(size_t)n * 4 + h] + GAT_EPS);
        m = 0.25f * m + b1[t];
        h1[t] = fmaxf(m, 0.f);
    }
    __syncthreads();
    const float* wr = &Wsh[t * 33];
    float a = 0.f;
#pragma unroll
    for (int k = 0; k < 32; k++) a += h1[k] * wr[k];
    xs[(size_t)n * 128 + t] = a;
    float vs = a * as_[t], vd = a * ad_[t];
#pragma unroll
    for (int off = 16; off; off >>= 1) {
        vs += __shfl_xor(vs, off);
        vd += __shfl_xor(vd, off);
    }
    if ((t & 31) == 0) {
        asrc[(size_t)n * 4 + (t >> 5)] = vs;
        adst[(size_t)n * 4 + (t >> 5)] = vd;
    }
}

// ---- layer-2 finalize -> output ----
__global__ void k_fin(const float* __restrict__ acc, const float* __restrict__ denom,
                      const float* __restrict__ b2, float* __restrict__ out, int N) {
    int i = blockIdx.x * blockDim.x + threadIdx.x;
    if (i >= N * 32) return;
    int n = i >> 5, c = i & 31;
    float m = 0.f;
#pragma unroll
    for (int h = 0; h < 4; h++)
        m += acc[(size_t)n * 128 + h * 32 + c] / (denom[(size_t)n * 4 + h] + GAT_EPS);
    m = 0.25f * m + b2[c];
    out[i] = fmaxf(m, 0.f);
}

extern "C" void kernel_launch(void* const* d_in, const int* in_sizes, int n_in,
                              void* d_out, int out_size, void* d_ws, size_t ws_size,
                              hipStream_t stream) {
    const float* x   = (const float*)d_in[0];
    const int*   ei  = (const int*)d_in[1];
    const float* ewt = (const float*)d_in[2];
    const float* w1  = (const float*)d_in[3];
    const float* we1 = (const float*)d_in[4];
    const float* as1 = (const float*)d_in[5];
    const float* ad1 = (const float*)d_in[6];
    const float* ae1 = (const float*)d_in[7];
    const float* b1  = (const float*)d_in[8];
    const float* w2  = (const float*)d_in[9];
    const float* we2 = (const float*)d_in[10];
    const float* as2 = (const float*)d_in[11];
    const float* ad2 = (const float*)d_in[12];
    const float* ae2 = (const float*)d_in[13];
    const float* b2  = (const float*)d_in[14];

    const int N = in_sizes[0] / 64;
    const int E = in_sizes[1] / 2;
    const int Etot = E + N;
    const int* srcI = ei;
    const int* dstI = ei + E;

    float* ws = (float*)d_ws;
    size_t off = 0;
    float* xs     = ws + off; off += (size_t)N * 128;
    float* acc    = ws + off; off += (size_t)N * 128;
    float* asrc   = ws + off; off += (size_t)N * 4;
    float* adst   = ws + off; off += (size_t)N * 4;
    float* denom  = ws + off; off += (size_t)N * 4;
    float* loopat = ws + off; off += (size_t)N;
    float* sums   = ws + off; off += (size_t)N;
    float* cnt    = ws + off; off += (size_t)N;
    float* wedot  = ws + off; off += 8;

    float* outF = (float*)d_out;

    // self-loop attrs
    hipMemsetAsync(sums, 0, (size_t)N * 2 * sizeof(float), stream);  // sums + cnt
    k_deg<<<(E + 255) / 256, 256, 0, stream>>>(dstI, ewt, sums, cnt, E);
    k_loopfin<<<(N + 255) / 256, 256, 0, stream>>>(sums, cnt, loopat, N);
    k_wedot<<<1, 128, 0, stream>>>(we1, ae1, we2, ae2, wedot);

    // layer 1
    k_gemm1<<<N, 128, 0, stream>>>(x, w1, as1, ad1, xs, asrc, adst, N);
    hipMemsetAsync(acc, 0, (size_t)N * 128 * sizeof(float), stream);
    hipMemsetAsync(denom, 0, (size_t)N * 4 * sizeof(float), stream);
    int eb = (int)(((long long)Etot * 32 + 255) / 256);
    k_edge<<<eb, 256, 0, stream>>>(srcI, dstI, ewt, loopat, xs, asrc, adst,
                                   wedot + 0, acc, denom, E, Etot);

    // layer-1 finalize + layer-2 GEMM
    k_node2<<<N, 128, 0, stream>>>(acc, denom, b1, w2, as2, ad2, xs, asrc, adst, N);

    // layer 2
    hipMemsetAsync(acc, 0, (size_t)N * 128 * sizeof(float), stream);
    hipMemsetAsync(denom, 0, (size_t)N * 4 * sizeof(float), stream);
    k_edge<<<eb, 256, 0, stream>>>(srcI, dstI, ewt, loopat, xs, asrc, adst,
                                   wedot + 4, acc, denom, E, Etot);
    k_fin<<<(N * 32 + 255) / 256, 256, 0, stream>>>(acc, denom, b2, outF, N);
}

// Round 2
// 1091.937 us; speedup vs baseline: 5.9256x; 5.9256x over previous
//
#include <hip/hip_runtime.h>
#include <cstddef>

#define GAT_EPS 1e-16f
#define SCAN_BS 256

// ---- histogram (in-degree) + edge_weight sums for self-loop fill='mean' ----
__global__ void k_deg(const int* __restrict__ dst, const float* __restrict__ ew,
                      float* __restrict__ sums, int* __restrict__ cnt, int E) {
    int i = blockIdx.x * blockDim.x + threadIdx.x;
    if (i < E) {
        int d = dst[i];
        atomicAdd(&sums[d], ew[i]);
        atomicAdd(&cnt[d], 1);
    }
}

__global__ void k_loopfin(const float* __restrict__ sums, const int* __restrict__ cnt,
                          float* __restrict__ loopat, int N) {
    int i = blockIdx.x * blockDim.x + threadIdx.x;
    if (i < N) loopat[i] = sums[i] / fmaxf((float)cnt[i], 1.0f);
}

// ---- per-head edge-attr dot constants ----
__global__ void k_wedot(const float* __restrict__ we1, const float* __restrict__ ae1,
                        const float* __restrict__ we2, const float* __restrict__ ae2,
                        float* __restrict__ wd) {
    int t = threadIdx.x;  // 128
    float v1 = we1[t] * ae1[t];
    float v2 = we2[t] * ae2[t];
#pragma unroll
    for (int off = 16; off; off >>= 1) {
        v1 += __shfl_xor(v1, off);
        v2 += __shfl_xor(v2, off);
    }
    if ((t & 31) == 0) { wd[t >> 5] = v1; wd[4 + (t >> 5)] = v2; }
}

// ---- exclusive scan of (cnt[i]+1) -> rowptr, 3-kernel hierarchy ----
__global__ void k_scanA(const int* __restrict__ cnt, int* __restrict__ incl,
                        int* __restrict__ bsum, int N) {
    __shared__ int sh[SCAN_BS];
    int i = blockIdx.x * SCAN_BS + threadIdx.x;
    int v = (i < N) ? cnt[i] + 1 : 0;
    sh[threadIdx.x] = v;
    __syncthreads();
    for (int off = 1; off < SCAN_BS; off <<= 1) {
        int t = (threadIdx.x >= off) ? sh[threadIdx.x - off] : 0;
        __syncthreads();
        sh[threadIdx.x] += t;
        __syncthreads();
    }
    if (i < N) incl[i] = sh[threadIdx.x];
    if (threadIdx.x == SCAN_BS - 1) bsum[blockIdx.x] = sh[threadIdx.x];
}

__global__ void k_scanB(int* __restrict__ bsum, int nb) {
    __shared__ int sh[512];
    int t = threadIdx.x;
    int v = (t < nb) ? bsum[t] : 0;
    sh[t] = v;
    __syncthreads();
    for (int off = 1; off < 512; off <<= 1) {
        int u = (t >= off) ? sh[t - off] : 0;
        __syncthreads();
        sh[t] += u;
        __syncthreads();
    }
    if (t < nb) bsum[t] = sh[t] - v;  // exclusive block offsets
}

__global__ void k_scanC(const int* __restrict__ cnt, const int* __restrict__ incl,
                        const int* __restrict__ bsum, int* __restrict__ rowptr,
                        int N, int Etot) {
    int i = blockIdx.x * SCAN_BS + threadIdx.x;
    if (i < N) rowptr[i] = bsum[blockIdx.x] + incl[i] - (cnt[i] + 1);
    if (i == N - 1) rowptr[N] = Etot;
}

// ---- scatter edges into CSR segments (one 4B atomic per edge) ----
__global__ void k_scatter(const int* __restrict__ src, const int* __restrict__ dst,
                          const float* __restrict__ ew, const float* __restrict__ loopat,
                          const int* __restrict__ rowptr, int* __restrict__ fill,
                          int* __restrict__ esrc, float* __restrict__ eea,
                          int E, int Etot) {
    int e = blockIdx.x * blockDim.x + threadIdx.x;
    if (e >= Etot) return;
    int s, d; float ea;
    if (e < E) { s = src[e]; d = dst[e]; ea = ew[e]; }
    else       { s = e - E; d = s;       ea = loopat[s]; }
    int pos = rowptr[d] + atomicAdd(&fill[d], 1);
    esrc[pos] = s;
    eea[pos] = ea;
}

// ---- layer-1 GEMM: xs = x @ W1^T (K=64), plus a_src/a_dst head reductions ----
__global__ void k_gemm1(const float* __restrict__ x, const float* __restrict__ W,
                        const float* __restrict__ as_, const float* __restrict__ ad_,
                        float* __restrict__ xs, float* __restrict__ asrc,
                        float* __restrict__ adst, int N) {
    int n = blockIdx.x;
    int t = threadIdx.x;  // 128
    __shared__ float Wsh[8320];
    __shared__ float xrow[64];
    for (int idx = t; idx < 8192; idx += 128) Wsh[idx + (idx >> 6)] = W[idx];
    if (t < 64) xrow[t] = x[(size_t)n * 64 + t];
    __syncthreads();
    const float* wr = &Wsh[t * 65];
    float a = 0.f;
#pragma unroll
    for (int k = 0; k < 64; k++) a += xrow[k] * wr[k];
    xs[(size_t)n * 128 + t] = a;
    float vs = a * as_[t], vd = a * ad_[t];
#pragma unroll
    for (int off = 16; off; off >>= 1) {
        vs += __shfl_xor(vs, off);
        vd += __shfl_xor(vd, off);
    }
    if ((t & 31) == 0) {
        asrc[(size_t)n * 4 + (t >> 5)] = vs;
        adst[(size_t)n * 4 + (t >> 5)] = vd;
    }
}

// ---- layer-2 GEMM: xs = h1 @ W2^T (K=32) ----
__global__ void k_gemm2(const float* __restrict__ h1, const float* __restrict__ W2,
                        const float* __restrict__ as_, const float* __restrict__ ad_,
                        float* __restrict__ xs, float* __restrict__ asrc,
                        float* __restrict__ adst, int N) {
    int n = blockIdx.x, t = threadIdx.x;  // 128
    __shared__ float Wsh[4224];
    __shared__ float hrow[32];
    for (int idx = t; idx < 4096; idx += 128) Wsh[idx + (idx >> 5)] = W2[idx];
    if (t < 32) hrow[t] = h1[(size_t)n * 32 + t];
    __syncthreads();
    const float* wr = &Wsh[t * 33];
    float a = 0.f;
#pragma unroll
    for (int k = 0; k < 32; k++) a += hrow[k] * wr[k];
    xs[(size_t)n * 128 + t] = a;
    float vs = a * as_[t], vd = a * ad_[t];
#pragma unroll
    for (int off = 16; off; off >>= 1) {
        vs += __shfl_xor(vs, off);
        vd += __shfl_xor(vd, off);
    }
    if ((t & 31) == 0) {
        asrc[(size_t)n * 4 + (t >> 5)] = vs;
        adst[(size_t)n * 4 + (t >> 5)] = vd;
    }
}

// ---- fused gather: per dst node, softmax-weighted aggregation + head-mean
//      + bias + relu, all in registers. One 64-lane wave per node. ----
__global__ void k_gather(const int* __restrict__ esrc, const float* __restrict__ eea,
                         const int* __restrict__ rowptr, const float* __restrict__ xs,
                         const float* __restrict__ asrc, const float* __restrict__ adst,
                         const float* __restrict__ wedot, const float* __restrict__ bias,
                         float* __restrict__ out, int N) {
    int node = blockIdx.x * (blockDim.x >> 6) + (threadIdx.x >> 6);
    if (node >= N) return;
    int l = threadIdx.x & 63;
    int h = l >> 4;                       // head for channels 2l, 2l+1
    float wd = wedot[h];
    float ad = adst[(size_t)node * 4 + h];
    int beg = rowptr[node], end = rowptr[node + 1];
    const float2* xs2 = reinterpret_cast<const float2*>(xs);

    float a0 = 0.f, a1 = 0.f, ds = 0.f;
    // 1-deep software pipeline: prefetch next edge's s/ea/asrc/xs row
    int s = esrc[beg];
    float ea = eea[beg];
    float as = asrc[(size_t)s * 4 + h];
    float2 v = xs2[(size_t)s * 64 + l];
    for (int i = beg; i < end; ++i) {
        int s1 = 0; float ea1 = 0.f, as1 = 0.f; float2 v1 = make_float2(0.f, 0.f);
        if (i + 1 < end) {
            s1 = esrc[i + 1];
            ea1 = eea[i + 1];
            as1 = asrc[(size_t)s1 * 4 + h];
            v1 = xs2[(size_t)s1 * 64 + l];
        }
        float al = as + ad + ea * wd;
        al = al > 0.f ? al : 0.2f * al;
        float w = expf(al);
        a0 += w * v.x;
        a1 += w * v.y;
        ds += w;
        s = s1; ea = ea1; as = as1; v = v1;
    }
    float inv = 1.f / (ds + GAT_EPS);
    a0 *= inv; a1 *= inv;
    // mean over heads: lanes l, l^16, l^32, l^48 hold the same channel pair
    a0 += __shfl_xor(a0, 16);
    a1 += __shfl_xor(a1, 16);
    a0 += __shfl_xor(a0, 32);
    a1 += __shfl_xor(a1, 32);
    if (l < 16) {
        int c0 = 2 * l;
        float r0 = fmaxf(0.25f * a0 + bias[c0], 0.f);
        float r1 = fmaxf(0.25f * a1 + bias[c0 + 1], 0.f);
        reinterpret_cast<float2*>(out)[(size_t)node * 16 + l] = make_float2(r0, r1);
    }
}

extern "C" void kernel_launch(void* const* d_in, const int* in_sizes, int n_in,
                              void* d_out, int out_size, void* d_ws, size_t ws_size,
                              hipStream_t stream) {
    const float* x   = (const float*)d_in[0];
    const int*   ei  = (const int*)d_in[1];
    const float* ewt = (const float*)d_in[2];
    const float* w1  = (const float*)d_in[3];
    const float* we1 = (const float*)d_in[4];
    const float* as1 = (const float*)d_in[5];
    const float* ad1 = (const float*)d_in[6];
    const float* ae1 = (const float*)d_in[7];
    const float* b1  = (const float*)d_in[8];
    const float* w2  = (const float*)d_in[9];
    const float* we2 = (const float*)d_in[10];
    const float* as2 = (const float*)d_in[11];
    const float* ad2 = (const float*)d_in[12];
    const float* ae2 = (const float*)d_in[13];
    const float* b2  = (const float*)d_in[14];

    const int N = in_sizes[0] / 64;
    const int E = in_sizes[1] / 2;
    const int Etot = E + N;
    const int* srcI = ei;
    const int* dstI = ei + E;
    const int nb = (N + SCAN_BS - 1) / SCAN_BS;

    char* base = (char*)d_ws;
    size_t off = 0;
    auto alloc = [&](size_t bytes) { char* p = base + off; off += (bytes + 15) & ~(size_t)15; return p; };
    float* xs     = (float*)alloc((size_t)N * 128 * sizeof(float));
    float* h1     = (float*)alloc((size_t)N * 32 * sizeof(float));
    float* asrc   = (float*)alloc((size_t)N * 4 * sizeof(float));
    float* adst   = (float*)alloc((size_t)N * 4 * sizeof(float));
    float* loopat = (float*)alloc((size_t)N * sizeof(float));
    float* sums   = (float*)alloc((size_t)N * sizeof(float));
    int*   cnt    = (int*)alloc((size_t)N * sizeof(int));
    int*   incl   = (int*)alloc((size_t)N * sizeof(int));
    int*   bsum   = (int*)alloc(512 * sizeof(int));
    int*   rowptr = (int*)alloc((size_t)(N + 1) * sizeof(int));
    int*   fill   = (int*)alloc((size_t)N * sizeof(int));
    int*   esrc   = (int*)alloc((size_t)Etot * sizeof(int));
    float* eea    = (float*)alloc((size_t)Etot * sizeof(float));
    float* wedot  = (float*)alloc(8 * sizeof(float));

    float* outF = (float*)d_out;

    // zero the accumulators the atomics need
    hipMemsetAsync(sums, 0, (size_t)N * sizeof(float), stream);
    hipMemsetAsync(cnt, 0, (size_t)N * sizeof(int), stream);
    hipMemsetAsync(fill, 0, (size_t)N * sizeof(int), stream);

    // CSR build + self-loop attrs
    k_deg<<<(E + 255) / 256, 256, 0, stream>>>(dstI, ewt, sums, cnt, E);
    k_loopfin<<<(N + 255) / 256, 256, 0, stream>>>(sums, cnt, loopat, N);
    k_wedot<<<1, 128, 0, stream>>>(we1, ae1, we2, ae2, wedot);
    k_scanA<<<nb, SCAN_BS, 0, stream>>>(cnt, incl, bsum, N);
    k_scanB<<<1, 512, 0, stream>>>(bsum, nb);
    k_scanC<<<nb, SCAN_BS, 0, stream>>>(cnt, incl, bsum, rowptr, N, Etot);
    k_scatter<<<(Etot + 255) / 256, 256, 0, stream>>>(srcI, dstI, ewt, loopat,
                                                      rowptr, fill, esrc, eea, E, Etot);

    // layer 1
    k_gemm1<<<N, 128, 0, stream>>>(x, w1, as1, ad1, xs, asrc, adst, N);
    int gb = (N + 3) / 4;  // 4 nodes (waves) per 256-thread block
    k_gather<<<gb, 256, 0, stream>>>(esrc, eea, rowptr, xs, asrc, adst,
                                     wedot + 0, b1, h1, N);

    // layer 2
    k_gemm2<<<N, 128, 0, stream>>>(h1, w2, as2, ad2, xs, asrc, adst, N);
    k_gather<<<gb, 256, 0, stream>>>(esrc, eea, rowptr, xs, asrc, adst,
                                     wedot + 4, b2, outF, N);
}